// Round 1
// 316.546 us; speedup vs baseline: 1.3323x; 1.3323x over previous
//
#include <hip/hip_runtime.h>
#include <math.h>

// Circular 3D cross-correlation via FFT, B=8, V=128.
// Z = v1 + i*v2 packed complex FFT; Hermitian split; G = F1*conj(F2); inverse.
// Storage convention unchanged from the passing rounds: each transformed axis
// held in bit-reversed order (DIF fwd: natural->bitrev; DIT inv:
// bitrev->natural); combine pairs k<->-k via bitrev7 per axis.
//
// Round-4 mechanics (WF16):
//  * 16 complex per lane, 8 lanes per 128-pt line, 8 lines per wave. Stages
//    h=64,32,16,8 are in-register butterflies; cross-lane stages h=4,2,1 go
//    through DPP (quad_perm / row_half_mirror) on the VALU pipe -- zero
//    ds_swizzle. Lane lq holds element low-part e = lq ^ 3*bit2(lq) so the
//    three cross masks are lane^7, lane^2, lane^1 (all DPP-expressible).
//  * One FFT run per thread per pass (1024 thr x 16 elem = 128x128 plane).
//  * LDS pitches 132 (planes) / 68 (K2 tiles): word-stride == 8 mod 32 gives
//    <=2 lanes/bank per 32-lane phase on both row-writes and column-reads.
//  * K2 x-pair search replaced by closed form; staging/writeback as float4.

#define V    128
#define V2   16384
#define V3   2097152
#define NB   8
#define PFP  132            // LDS pitch (float2) for 128-wide planes (K1/K3)
#define PH2  68             // LDS pitch (float2) for 64-wide K2 tiles
#define TILE2 (V * PH2)

__device__ __forceinline__ int bitrev7(int x) {
  return (int)(__brev((unsigned)x) >> 25);
}
__device__ __forceinline__ int negrev(int j) {
  int k = bitrev7(j);
  return bitrev7((V - k) & (V - 1));
}

__device__ __forceinline__ float2 cmul(float2 a, float2 b) {
  return make_float2(a.x * b.x - a.y * b.y, a.x * b.y + a.y * b.x);
}
__device__ __forceinline__ float2 cmulc(float2 a, float2 b) {  // a * conj(b)
  return make_float2(a.x * b.x + a.y * b.y, a.y * b.x - a.x * b.y);
}
__device__ __forceinline__ float2 csqr(float2 a) {
  return make_float2(a.x * a.x - a.y * a.y, 2.0f * a.x * a.y);
}
__device__ __forceinline__ float2 f2add(float2 a, float2 b) {
  return make_float2(a.x + b.x, a.y + b.y);
}
__device__ __forceinline__ float2 f2sub(float2 a, float2 b) {
  return make_float2(a.x - b.x, a.y - b.y);
}
__device__ __forceinline__ float2 NI(float2 z) { return make_float2(z.y, -z.x); }  // z*(-i)
__device__ __forceinline__ float2 PI(float2 z) { return make_float2(-z.y, z.x); }  // z*(+i)

// DPP lane exchange: 0xB1 = quad_perm[1,0,3,2] (lane^1),
// 0x4E = quad_perm[2,3,0,1] (lane^2), 0x141 = row_half_mirror (lane^7).
template <int CTRL>
__device__ __forceinline__ float dppf(float v) {
  return __int_as_float(
      __builtin_amdgcn_update_dpp(0, __float_as_int(v), CTRL, 0xF, 0xF, true));
}
template <int CTRL>
__device__ __forceinline__ float2 dpp2(float2 v) {
  return make_float2(dppf<CTRL>(v.x), dppf<CTRL>(v.y));
}

// 128-pt radix-2 FFT: lane lq (0..7 in group) holds elements n = e + 8j,
// j=0..15, e = lq ^ 3*bit2(lq). Fwd DIF h=64..8 in-lane, h=4,2,1 via DPP.
// Inv DIT mirrored with conjugated twiddles (cmulc on the same table).
struct WF16 {
  float2 T64[4], T32[2], T16a, T16b, T8w, ts4, ts2;
  float sg4, sg2, sg1;
  bool up4, up2;
  int e;

  __device__ void init(int lq) {
    e = lq ^ (((lq >> 2) & 1) * 3);
    const float k = -6.28318530717958647692f / 128.0f;
    float2 w1 = make_float2(cosf(k * (float)e), sinf(k * (float)e));  // W128^e
    const float C1 = 0.92387953251128675613f;   // cos(pi/8)
    const float S1 = 0.38268343236508977173f;   // sin(pi/8)
    const float R  = 0.70710678118654752440f;
    T64[0] = w1;                                  // W128^{e+8j} = w1*W16^j
    T64[1] = cmul(w1, make_float2(C1, -S1));
    T64[2] = cmul(w1, make_float2(R, -R));
    T64[3] = cmul(w1, make_float2(S1, -C1));      // j>=4 derived via *(-i)
    float2 w2 = csqr(w1);                         // W128^{2e}
    T32[0] = w2;
    T32[1] = cmul(w2, make_float2(R, -R));        // j0>=2 derived via *(-i)
    T16a = csqr(w2);                              // W128^{4e}
    T16b = NI(T16a);                              // W128^{4e+32}
    T8w = csqr(T16a);                             // W128^{8e}
    up4 = (e >> 2) & 1;
    up2 = (e >> 1) & 1;
    const bool up1 = e & 1;
    sg4 = up4 ? -1.0f : 1.0f;
    sg2 = up2 ? -1.0f : 1.0f;
    sg1 = up1 ? -1.0f : 1.0f;
    const int m4 = e & 3;
    float2 w8p = (m4 == 0) ? make_float2(1.0f, 0.0f)
               : (m4 == 1) ? make_float2(R, -R)
               : (m4 == 2) ? make_float2(0.0f, -1.0f)
                           : make_float2(-R, -R);
    ts4 = up4 ? w8p : make_float2(1.0f, 0.0f);    // W8^{e&3} on upper half
    ts2 = (up2 && (e & 1)) ? make_float2(0.0f, -1.0f) : make_float2(1.0f, 0.0f);
  }

  __device__ __forceinline__ void fwd(float2 c[16]) const {
#pragma unroll
    for (int j = 0; j < 8; ++j) {                 // h=64
      float2 u = c[j], v = c[j + 8];
      c[j] = f2add(u, v);
      float2 t = cmul(f2sub(u, v), T64[j & 3]);
      c[j + 8] = (j < 4) ? t : NI(t);
    }
#pragma unroll
    for (int g = 0; g < 2; ++g) {                 // h=32
#pragma unroll
      for (int j0 = 0; j0 < 4; ++j0) {
        const int j = g * 8 + j0;
        float2 u = c[j], v = c[j + 4];
        c[j] = f2add(u, v);
        float2 t = cmul(f2sub(u, v), T32[j0 & 1]);
        c[j + 4] = (j0 < 2) ? t : NI(t);
      }
    }
#pragma unroll
    for (int g = 0; g < 4; ++g) {                 // h=16
#pragma unroll
      for (int j0 = 0; j0 < 2; ++j0) {
        const int j = g * 4 + j0;
        float2 u = c[j], v = c[j + 2];
        c[j] = f2add(u, v);
        c[j + 2] = cmul(f2sub(u, v), j0 ? T16b : T16a);
      }
    }
#pragma unroll
    for (int j = 0; j < 16; j += 2) {             // h=8
      float2 u = c[j], v = c[j + 1];
      c[j] = f2add(u, v);
      c[j + 1] = cmul(f2sub(u, v), T8w);
    }
#pragma unroll
    for (int j = 0; j < 16; ++j) {                // h=4 : lane^7
      float2 p = dpp2<0x141>(c[j]);
      float2 t = make_float2(fmaf(c[j].x, sg4, p.x), fmaf(c[j].y, sg4, p.y));
      c[j] = cmul(t, ts4);
    }
#pragma unroll
    for (int j = 0; j < 16; ++j) {                // h=2 : lane^2
      float2 p = dpp2<0x4E>(c[j]);
      float2 t = make_float2(fmaf(c[j].x, sg2, p.x), fmaf(c[j].y, sg2, p.y));
      c[j] = cmul(t, ts2);
    }
#pragma unroll
    for (int j = 0; j < 16; ++j) {                // h=1 : lane^1 (tw = 1)
      float2 p = dpp2<0xB1>(c[j]);
      c[j] = make_float2(fmaf(c[j].x, sg1, p.x), fmaf(c[j].y, sg1, p.y));
    }
  }

  __device__ __forceinline__ void inv(float2 c[16]) const {
#pragma unroll
    for (int j = 0; j < 16; ++j) {                // h=1
      float2 p = dpp2<0xB1>(c[j]);
      c[j] = make_float2(fmaf(c[j].x, sg1, p.x), fmaf(c[j].y, sg1, p.y));
    }
#pragma unroll
    for (int j = 0; j < 16; ++j) {                // h=2
      float2 m = cmulc(c[j], ts2);
      float2 q = make_float2(up2 ? m.x : c[j].x, up2 ? m.y : c[j].y);
      float2 p = dpp2<0x4E>(q);
      c[j] = make_float2(fmaf(q.x, sg2, p.x), fmaf(q.y, sg2, p.y));
    }
#pragma unroll
    for (int j = 0; j < 16; ++j) {                // h=4
      float2 m = cmulc(c[j], ts4);
      float2 q = make_float2(up4 ? m.x : c[j].x, up4 ? m.y : c[j].y);
      float2 p = dpp2<0x141>(q);
      c[j] = make_float2(fmaf(q.x, sg4, p.x), fmaf(q.y, sg4, p.y));
    }
#pragma unroll
    for (int j = 0; j < 16; j += 2) {             // h=8
      float2 m = cmulc(c[j + 1], T8w);
      float2 u = c[j];
      c[j] = f2add(u, m);
      c[j + 1] = f2sub(u, m);
    }
#pragma unroll
    for (int g = 0; g < 4; ++g) {                 // h=16
#pragma unroll
      for (int j0 = 0; j0 < 2; ++j0) {
        const int j = g * 4 + j0;
        float2 m = cmulc(c[j + 2], j0 ? T16b : T16a);
        float2 u = c[j];
        c[j] = f2add(u, m);
        c[j + 2] = f2sub(u, m);
      }
    }
#pragma unroll
    for (int g = 0; g < 2; ++g) {                 // h=32
#pragma unroll
      for (int j0 = 0; j0 < 4; ++j0) {
        const int j = g * 8 + j0;
        float2 m0 = cmulc(c[j + 4], T32[j0 & 1]);
        float2 m = (j0 < 2) ? m0 : PI(m0);        // conj(T*(-i)) = conj(T)*i
        float2 u = c[j];
        c[j] = f2add(u, m);
        c[j + 4] = f2sub(u, m);
      }
    }
#pragma unroll
    for (int j = 0; j < 8; ++j) {                 // h=64
      float2 m0 = cmulc(c[j + 8], T64[j & 3]);
      float2 m = (j < 4) ? m0 : PI(m0);
      float2 u = c[j];
      c[j] = f2add(u, m);
      c[j + 8] = f2sub(u, m);
    }
  }
};

// K1: per (b, z1) plane. x-FFT streamed from global; y-FFT from LDS columns;
// results written straight to Z(b, x, z1, y) (y-contiguous).
__global__ __launch_bounds__(1024) void k_fwd_xy(const float* __restrict__ v1,
                                                 const float* __restrict__ v2,
                                                 float2* __restrict__ Z) {
  __shared__ float2 s[V * PFP];
  const int tid = threadIdx.x, lane = tid & 63, wave = tid >> 6;
  const int o = lane >> 3, lq = lane & 7;
  const int b = blockIdx.x >> 7, z1 = blockIdx.x & 127;
  WF16 F;
  F.init(lq);
  const int e = F.e;
  float2 c[16];
  {
    const int y = wave * 8 + o;
    const size_t g = (size_t)b * V3 + (size_t)z1 * V2 + (size_t)y * V;
#pragma unroll
    for (int j = 0; j < 16; ++j) {
      const int n = e + 8 * j;
      c[j] = make_float2(v1[g + n], v2[g + n]);
    }
    F.fwd(c);
#pragma unroll
    for (int j = 0; j < 16; ++j) s[y * PFP + e + 8 * j] = c[j];
  }
  __syncthreads();
  {
    const int x = wave * 8 + o;
#pragma unroll
    for (int j = 0; j < 16; ++j) c[j] = s[(e + 8 * j) * PFP + x];
    F.fwd(c);
    const size_t zb = ((size_t)(b * V + x) * V + z1) * V;
#pragma unroll
    for (int j = 0; j < 16; ++j) Z[zb + e + 8 * j] = c[j];
  }
}

// K2: per (b, x-pair, y-half). Contiguous (z,y) tiles; fwd z-FFT + combine +
// inv z-FFT in LDS. Pair (xA,xB): k<->128-k in bitrev space, closed form.
__global__ __launch_bounds__(1024) void k_z_fused(float2* __restrict__ Z) {
  __shared__ float2 T[2 * TILE2];
  const int tid = threadIdx.x, lane = tid & 63, wave = tid >> 6;
  const int o = lane >> 3, lq = lane & 7;
  const int blk = blockIdx.x;
  const int b = blk / 130, r = blk % 130, g = r >> 1, yh = r & 1;
  int xA, xB;
  if (g < 2) {                 // k=0 -> x=0, k=64 -> x=1: self-paired
    xA = xB = g;
  } else {
    const int k = g - 1;       // 1..63
    xA = bitrev7(k);
    xB = bitrev7(V - k);       // = negrev(xA)
  }
  const bool self = (xA == xB);
  WF16 F;
  F.init(lq);
  const int e = F.e;
  const size_t baseA = (size_t)(b * V + xA) * V2 + yh * 64;
  const size_t baseB = (size_t)(b * V + xB) * V2 + yh * 64;

  for (int p = tid; p < 4096; p += 1024) {
    const int z = p >> 5, y = (p & 31) << 1;
    *(float4*)&T[z * PH2 + y] = *(const float4*)&Z[baseA + (size_t)z * V + y];
  }
  if (!self) {
    for (int p = tid; p < 4096; p += 1024) {
      const int z = p >> 5, y = (p & 31) << 1;
      *(float4*)&T[TILE2 + z * PH2 + y] =
          *(const float4*)&Z[baseB + (size_t)z * V + y];
    }
  }
  __syncthreads();

  const int col = wave * 8 + o;            // 0..127 (2 tiles x 64 cols)
  const int tb = (col >> 6) * TILE2;
  const int yc = col & 63;
  const bool active = (!self) || (wave < 8);   // wave-uniform
  float2 c[16];
  if (active) {                            // forward z-FFT
#pragma unroll
    for (int j = 0; j < 16; ++j) c[j] = T[tb + (e + 8 * j) * PH2 + yc];
    F.fwd(c);
#pragma unroll
    for (int j = 0; j < 16; ++j) T[tb + (e + 8 * j) * PH2 + yc] = c[j];
  }
  __syncthreads();

  if (!self) {
    for (int p = tid; p < 8192; p += 1024) {
      const int z = p >> 6, y = p & 63;
      const int zm = negrev(z), ym = negrev(yh * 64 + y) & 63;
      const float2 a  = T[z * PH2 + y];
      const float2 bb = T[TILE2 + zm * PH2 + ym];
      const float f1r = 0.5f * (a.x + bb.x), f1i = 0.5f * (a.y - bb.y);
      const float f2r = 0.5f * (a.y + bb.y), f2i = 0.5f * (bb.x - a.x);
      const float gr = f1r * f2r + f1i * f2i;
      const float gi = f1i * f2r - f1r * f2i;
      T[z * PH2 + y] = make_float2(gr, gi);
      T[TILE2 + zm * PH2 + ym] = make_float2(gr, -gi);
    }
  } else {
    for (int p = tid; p < 8192; p += 1024) {
      const int z = p >> 6, y = p & 63;
      const int zm = negrev(z), ym = negrev(yh * 64 + y) & 63;
      const int pm = zm * 64 + ym;
      if (pm < p) continue;
      const float2 a  = T[z * PH2 + y];
      const float2 bb = T[zm * PH2 + ym];
      const float f1r = 0.5f * (a.x + bb.x), f1i = 0.5f * (a.y - bb.y);
      const float f2r = 0.5f * (a.y + bb.y), f2i = 0.5f * (bb.x - a.x);
      const float gr = f1r * f2r + f1i * f2i;
      const float gi = f1i * f2r - f1r * f2i;
      T[z * PH2 + y] = make_float2(gr, gi);
      if (pm != p) T[zm * PH2 + ym] = make_float2(gr, -gi);
    }
  }
  __syncthreads();

  if (active) {                            // inverse z-FFT
#pragma unroll
    for (int j = 0; j < 16; ++j) c[j] = T[tb + (e + 8 * j) * PH2 + yc];
    F.inv(c);
#pragma unroll
    for (int j = 0; j < 16; ++j) T[tb + (e + 8 * j) * PH2 + yc] = c[j];
  }
  __syncthreads();

  for (int p = tid; p < 4096; p += 1024) {
    const int z = p >> 5, y = (p & 31) << 1;
    *(float4*)&Z[baseA + (size_t)z * V + y] = *(const float4*)&T[z * PH2 + y];
  }
  if (!self) {
    for (int p = tid; p < 4096; p += 1024) {
      const int z = p >> 5, y = (p & 31) << 1;
      *(float4*)&Z[baseB + (size_t)z * V + y] =
          *(const float4*)&T[TILE2 + z * PH2 + y];
    }
  }
}

// K3: per (b, z1) plane. Inverse y-FFT streamed from Z(b,x,z1,y-contig);
// inverse x-FFT from LDS rows; real part * 1/V^3 to out(b,z1,y,x).
__global__ __launch_bounds__(1024) void k_inv_xy(const float2* __restrict__ Z,
                                                 float* __restrict__ out) {
  __shared__ float2 s[V * PFP];
  const int tid = threadIdx.x, lane = tid & 63, wave = tid >> 6;
  const int o = lane >> 3, lq = lane & 7;
  const int b = blockIdx.x >> 7, z1 = blockIdx.x & 127;
  WF16 F;
  F.init(lq);
  const int e = F.e;
  float2 c[16];
  {
    const int x = wave * 8 + o;
    const size_t zb = ((size_t)(b * V + x) * V + z1) * V;
#pragma unroll
    for (int j = 0; j < 16; ++j) c[j] = Z[zb + e + 8 * j];
    F.inv(c);
#pragma unroll
    for (int j = 0; j < 16; ++j) s[(e + 8 * j) * PFP + x] = c[j];
  }
  __syncthreads();
  const float sc = 1.0f / 2097152.0f;  // 1/V^3
  {
    const int y = wave * 8 + o;
#pragma unroll
    for (int j = 0; j < 16; ++j) c[j] = s[y * PFP + e + 8 * j];
    F.inv(c);
    const size_t gg = (size_t)b * V3 + (size_t)z1 * V2 + (size_t)y * V;
#pragma unroll
    for (int j = 0; j < 16; ++j) out[gg + e + 8 * j] = c[j].x * sc;
  }
}

extern "C" void kernel_launch(void* const* d_in, const int* in_sizes, int n_in,
                              void* d_out, int out_size, void* d_ws, size_t ws_size,
                              hipStream_t stream) {
  const float* v1 = (const float*)d_in[0];
  const float* v2 = (const float*)d_in[1];
  float* out = (float*)d_out;
  float2* Z  = (float2*)d_ws;  // NB*V3*8 = 128 MiB

  k_fwd_xy<<<NB * V, 1024, 0, stream>>>(v1, v2, Z);
  k_z_fused<<<NB * 130, 1024, 0, stream>>>(Z);   // 8 b x 65 x-groups x 2 y-halves
  k_inv_xy<<<NB * V, 1024, 0, stream>>>(Z, out);
}

// Round 2
// 310.817 us; speedup vs baseline: 1.3568x; 1.0184x over previous
//
#include <hip/hip_runtime.h>
#include <math.h>

// Circular 3D cross-correlation via FFT, B=8, V=128.
// Z = v1 + i*v2 packed complex FFT; Hermitian split; G = F1*conj(F2); inverse.
// Storage: each transformed axis in bit-reversed order; pairs k<->-k via
// bitrev7 per axis (same convention as all passing rounds).
//
// Round-5 mechanics:
//  * K2 rebuilt on quarter-slices: block holds TWO 128x32 (z,y) slices
//    (70 KB LDS, 512 thr) -> 2 blocks/CU so phases of independent blocks
//    overlap. Pairing: even-ky slices (storage bit6=0) keep bit1 under
//    k->128-k, so same-q slices pair; odd-ky slices flip bit1, so q=0 of
//    tile A pairs with q=1 of tile B. Self x in {0,1} handled uniformly.
//    All 8 waves active in every block (64 FFT columns).
//  * K1/K3: 2 z-planes per block; plane-1 global loads prefetched into
//    registers during plane-0 second pass (hides HBM latency under VALU).
//  * FFT core (WF16) unchanged: 16 elem/lane, DPP-only cross-lane stages.

#define V    128
#define V2   16384
#define V3   2097152
#define NB   8
#define PFP  132            // LDS pitch (float2) for 128-wide planes (K1/K3)
#define PH3  34             // LDS pitch (float2) for 32-wide K2 slices
#define SLICE (V * PH3)     // 4352 float2 = 34816 B

__device__ __forceinline__ int bitrev7(int x) {
  return (int)(__brev((unsigned)x) >> 25);
}
__device__ __forceinline__ int negrev(int j) {
  int k = bitrev7(j);
  return bitrev7((V - k) & (V - 1));
}

__device__ __forceinline__ float2 cmul(float2 a, float2 b) {
  return make_float2(a.x * b.x - a.y * b.y, a.x * b.y + a.y * b.x);
}
__device__ __forceinline__ float2 cmulc(float2 a, float2 b) {  // a * conj(b)
  return make_float2(a.x * b.x + a.y * b.y, a.y * b.x - a.x * b.y);
}
__device__ __forceinline__ float2 csqr(float2 a) {
  return make_float2(a.x * a.x - a.y * a.y, 2.0f * a.x * a.y);
}
__device__ __forceinline__ float2 f2add(float2 a, float2 b) {
  return make_float2(a.x + b.x, a.y + b.y);
}
__device__ __forceinline__ float2 f2sub(float2 a, float2 b) {
  return make_float2(a.x - b.x, a.y - b.y);
}
__device__ __forceinline__ float2 NI(float2 z) { return make_float2(z.y, -z.x); }  // z*(-i)
__device__ __forceinline__ float2 PI(float2 z) { return make_float2(-z.y, z.x); }  // z*(+i)

// DPP lane exchange: 0xB1 = quad_perm[1,0,3,2] (lane^1),
// 0x4E = quad_perm[2,3,0,1] (lane^2), 0x141 = row_half_mirror (lane^7).
template <int CTRL>
__device__ __forceinline__ float dppf(float v) {
  return __int_as_float(
      __builtin_amdgcn_update_dpp(0, __float_as_int(v), CTRL, 0xF, 0xF, true));
}
template <int CTRL>
__device__ __forceinline__ float2 dpp2(float2 v) {
  return make_float2(dppf<CTRL>(v.x), dppf<CTRL>(v.y));
}

// 128-pt radix-2 FFT: lane lq (0..7 in group) holds elements n = e + 8j,
// j=0..15, e = lq ^ 3*bit2(lq). Fwd DIF h=64..8 in-lane, h=4,2,1 via DPP.
// Inv DIT mirrored with conjugated twiddles (cmulc on the same table).
struct WF16 {
  float2 T64[4], T32[2], T16a, T16b, T8w, ts4, ts2;
  float sg4, sg2, sg1;
  bool up4, up2;
  int e;

  __device__ void init(int lq) {
    e = lq ^ (((lq >> 2) & 1) * 3);
    const float k = -6.28318530717958647692f / 128.0f;
    float2 w1 = make_float2(cosf(k * (float)e), sinf(k * (float)e));  // W128^e
    const float C1 = 0.92387953251128675613f;   // cos(pi/8)
    const float S1 = 0.38268343236508977173f;   // sin(pi/8)
    const float R  = 0.70710678118654752440f;
    T64[0] = w1;                                  // W128^{e+8j} = w1*W16^j
    T64[1] = cmul(w1, make_float2(C1, -S1));
    T64[2] = cmul(w1, make_float2(R, -R));
    T64[3] = cmul(w1, make_float2(S1, -C1));      // j>=4 derived via *(-i)
    float2 w2 = csqr(w1);                         // W128^{2e}
    T32[0] = w2;
    T32[1] = cmul(w2, make_float2(R, -R));        // j0>=2 derived via *(-i)
    T16a = csqr(w2);                              // W128^{4e}
    T16b = NI(T16a);                              // W128^{4e+32}
    T8w = csqr(T16a);                             // W128^{8e}
    up4 = (e >> 2) & 1;
    up2 = (e >> 1) & 1;
    const bool up1 = e & 1;
    sg4 = up4 ? -1.0f : 1.0f;
    sg2 = up2 ? -1.0f : 1.0f;
    sg1 = up1 ? -1.0f : 1.0f;
    const int m4 = e & 3;
    float2 w8p = (m4 == 0) ? make_float2(1.0f, 0.0f)
               : (m4 == 1) ? make_float2(R, -R)
               : (m4 == 2) ? make_float2(0.0f, -1.0f)
                           : make_float2(-R, -R);
    ts4 = up4 ? w8p : make_float2(1.0f, 0.0f);    // W8^{e&3} on upper half
    ts2 = (up2 && (e & 1)) ? make_float2(0.0f, -1.0f) : make_float2(1.0f, 0.0f);
  }

  __device__ __forceinline__ void fwd(float2 c[16]) const {
#pragma unroll
    for (int j = 0; j < 8; ++j) {                 // h=64
      float2 u = c[j], v = c[j + 8];
      c[j] = f2add(u, v);
      float2 t = cmul(f2sub(u, v), T64[j & 3]);
      c[j + 8] = (j < 4) ? t : NI(t);
    }
#pragma unroll
    for (int g = 0; g < 2; ++g) {                 // h=32
#pragma unroll
      for (int j0 = 0; j0 < 4; ++j0) {
        const int j = g * 8 + j0;
        float2 u = c[j], v = c[j + 4];
        c[j] = f2add(u, v);
        float2 t = cmul(f2sub(u, v), T32[j0 & 1]);
        c[j + 4] = (j0 < 2) ? t : NI(t);
      }
    }
#pragma unroll
    for (int g = 0; g < 4; ++g) {                 // h=16
#pragma unroll
      for (int j0 = 0; j0 < 2; ++j0) {
        const int j = g * 4 + j0;
        float2 u = c[j], v = c[j + 2];
        c[j] = f2add(u, v);
        c[j + 2] = cmul(f2sub(u, v), j0 ? T16b : T16a);
      }
    }
#pragma unroll
    for (int j = 0; j < 16; j += 2) {             // h=8
      float2 u = c[j], v = c[j + 1];
      c[j] = f2add(u, v);
      c[j + 1] = cmul(f2sub(u, v), T8w);
    }
#pragma unroll
    for (int j = 0; j < 16; ++j) {                // h=4 : lane^7
      float2 p = dpp2<0x141>(c[j]);
      float2 t = make_float2(fmaf(c[j].x, sg4, p.x), fmaf(c[j].y, sg4, p.y));
      c[j] = cmul(t, ts4);
    }
#pragma unroll
    for (int j = 0; j < 16; ++j) {                // h=2 : lane^2
      float2 p = dpp2<0x4E>(c[j]);
      float2 t = make_float2(fmaf(c[j].x, sg2, p.x), fmaf(c[j].y, sg2, p.y));
      c[j] = cmul(t, ts2);
    }
#pragma unroll
    for (int j = 0; j < 16; ++j) {                // h=1 : lane^1 (tw = 1)
      float2 p = dpp2<0xB1>(c[j]);
      c[j] = make_float2(fmaf(c[j].x, sg1, p.x), fmaf(c[j].y, sg1, p.y));
    }
  }

  __device__ __forceinline__ void inv(float2 c[16]) const {
#pragma unroll
    for (int j = 0; j < 16; ++j) {                // h=1
      float2 p = dpp2<0xB1>(c[j]);
      c[j] = make_float2(fmaf(c[j].x, sg1, p.x), fmaf(c[j].y, sg1, p.y));
    }
#pragma unroll
    for (int j = 0; j < 16; ++j) {                // h=2
      float2 m = cmulc(c[j], ts2);
      float2 q = make_float2(up2 ? m.x : c[j].x, up2 ? m.y : c[j].y);
      float2 p = dpp2<0x4E>(q);
      c[j] = make_float2(fmaf(q.x, sg2, p.x), fmaf(q.y, sg2, p.y));
    }
#pragma unroll
    for (int j = 0; j < 16; ++j) {                // h=4
      float2 m = cmulc(c[j], ts4);
      float2 q = make_float2(up4 ? m.x : c[j].x, up4 ? m.y : c[j].y);
      float2 p = dpp2<0x141>(q);
      c[j] = make_float2(fmaf(q.x, sg4, p.x), fmaf(q.y, sg4, p.y));
    }
#pragma unroll
    for (int j = 0; j < 16; j += 2) {             // h=8
      float2 m = cmulc(c[j + 1], T8w);
      float2 u = c[j];
      c[j] = f2add(u, m);
      c[j + 1] = f2sub(u, m);
    }
#pragma unroll
    for (int g = 0; g < 4; ++g) {                 // h=16
#pragma unroll
      for (int j0 = 0; j0 < 2; ++j0) {
        const int j = g * 4 + j0;
        float2 m = cmulc(c[j + 2], j0 ? T16b : T16a);
        float2 u = c[j];
        c[j] = f2add(u, m);
        c[j + 2] = f2sub(u, m);
      }
    }
#pragma unroll
    for (int g = 0; g < 2; ++g) {                 // h=32
#pragma unroll
      for (int j0 = 0; j0 < 4; ++j0) {
        const int j = g * 8 + j0;
        float2 m0 = cmulc(c[j + 4], T32[j0 & 1]);
        float2 m = (j0 < 2) ? m0 : PI(m0);        // conj(T*(-i)) = conj(T)*i
        float2 u = c[j];
        c[j] = f2add(u, m);
        c[j + 4] = f2sub(u, m);
      }
    }
#pragma unroll
    for (int j = 0; j < 8; ++j) {                 // h=64
      float2 m0 = cmulc(c[j + 8], T64[j & 3]);
      float2 m = (j < 4) ? m0 : PI(m0);
      float2 u = c[j];
      c[j] = f2add(u, m);
      c[j + 8] = f2sub(u, m);
    }
  }
};

// K1: per (b, z-plane-pair). x-FFT streamed from global; y-FFT from LDS
// columns; results to Z(b, x, z, y) (y-contiguous). Plane-1 loads prefetched
// into registers during plane-0 second pass.
__global__ __launch_bounds__(1024) void k_fwd_xy(const float* __restrict__ v1,
                                                 const float* __restrict__ v2,
                                                 float2* __restrict__ Z) {
  __shared__ float2 s[V * PFP];
  const int tid = threadIdx.x, lane = tid & 63, wave = tid >> 6;
  const int o = lane >> 3, lq = lane & 7;
  const int b = blockIdx.x >> 6, zp = blockIdx.x & 63;
  const int z1 = zp * 2;
  WF16 F;
  F.init(lq);
  const int e = F.e;
  const int row = wave * 8 + o;   // y in pass 1, x in pass 2
  float2 c[16];
  {                               // plane 0: rows
    const size_t g = (size_t)b * V3 + (size_t)z1 * V2 + (size_t)row * V;
#pragma unroll
    for (int j = 0; j < 16; ++j) {
      const int n = e + 8 * j;
      c[j] = make_float2(v1[g + n], v2[g + n]);
    }
    F.fwd(c);
#pragma unroll
    for (int j = 0; j < 16; ++j) s[row * PFP + e + 8 * j] = c[j];
  }
  __syncthreads();
  float pa[16], pb[16];           // prefetch plane 1 rows
  {
    const size_t g = (size_t)b * V3 + (size_t)(z1 + 1) * V2 + (size_t)row * V;
#pragma unroll
    for (int j = 0; j < 16; ++j) {
      const int n = e + 8 * j;
      pa[j] = v1[g + n];
      pb[j] = v2[g + n];
    }
  }
  {                               // plane 0: columns
    float2 d[16];
#pragma unroll
    for (int j = 0; j < 16; ++j) d[j] = s[(e + 8 * j) * PFP + row];
    F.fwd(d);
    const size_t zb = ((size_t)(b * V + row) * V + z1) * V;
#pragma unroll
    for (int j = 0; j < 16; ++j) Z[zb + e + 8 * j] = d[j];
  }
  __syncthreads();
  {                               // plane 1: rows (from prefetch)
#pragma unroll
    for (int j = 0; j < 16; ++j) c[j] = make_float2(pa[j], pb[j]);
    F.fwd(c);
#pragma unroll
    for (int j = 0; j < 16; ++j) s[row * PFP + e + 8 * j] = c[j];
  }
  __syncthreads();
  {                               // plane 1: columns
    float2 d[16];
#pragma unroll
    for (int j = 0; j < 16; ++j) d[j] = s[(e + 8 * j) * PFP + row];
    F.fwd(d);
    const size_t zb = ((size_t)(b * V + row) * V + (z1 + 1)) * V;
#pragma unroll
    for (int j = 0; j < 16; ++j) Z[zb + e + 8 * j] = d[j];
  }
}

// K2: per (b, slice-pair). Two 128x32 (z,y) quarter-slices in LDS; fwd z-FFT
// + Hermitian combine + inv z-FFT. Even-ky slices pair same-q; odd-ky slices
// pair q0<->q1 across the x-pair; x in {0,1} self-paired.
__global__ __launch_bounds__(512, 4) void k_z_fused(float2* __restrict__ Z) {
  __shared__ float2 T[2 * SLICE];   // 69632 B -> 2 blocks/CU
  const int tid = threadIdx.x, lane = tid & 63, wave = tid >> 6;
  const int o = lane >> 3, lq = lane & 7;
  const int blk = blockIdx.x;
  const int b = blk >> 8, idx = blk & 255;
  int x0, x1, jb0, jb1;
  bool within = false;
  {
    const int h = idx >> 7, r2 = idx & 127;   // h = ky parity (storage bit6)
    if (r2 < 126) {
      const int k = (r2 >> 1) + 1, cc = r2 & 1;
      const int xa = bitrev7(k), xb = bitrev7(V - k);
      if (h == 0) { x0 = xa; x1 = xb; jb0 = cc * 32; jb1 = cc * 32; }
      else { x0 = cc ? xb : xa; x1 = cc ? xa : xb; jb0 = 64; jb1 = 96; }
    } else {
      x0 = x1 = r2 - 126;                     // self-paired x = 0 or 1
      if (h == 0) { jb0 = 0; jb1 = 32; within = true; }
      else { jb0 = 64; jb1 = 96; }
    }
  }
  WF16 F;
  F.init(lq);
  const int e = F.e;
  const size_t base0 = (size_t)(b * V + x0) * V2 + jb0;
  const size_t base1 = (size_t)(b * V + x1) * V2 + jb1;

  for (int p = tid; p < 2048; p += 512) {       // stage in
    const int z = p >> 4, w = (p & 15) << 1;
    *(float4*)&T[z * PH3 + w] = *(const float4*)&Z[base0 + (size_t)z * V + w];
  }
  for (int p = tid; p < 2048; p += 512) {
    const int z = p >> 4, w = (p & 15) << 1;
    *(float4*)&T[SLICE + z * PH3 + w] =
        *(const float4*)&Z[base1 + (size_t)z * V + w];
  }
  __syncthreads();

  const int col = wave * 8 + o;                 // 0..63: 2 slices x 32 cols
  const int tb = (col >> 5) * SLICE, yc = col & 31;
  float2 c[16];
#pragma unroll
  for (int j = 0; j < 16; ++j) c[j] = T[tb + (e + 8 * j) * PH3 + yc];
  F.fwd(c);
#pragma unroll
  for (int j = 0; j < 16; ++j) T[tb + (e + 8 * j) * PH3 + yc] = c[j];
  __syncthreads();

  if (!within) {                                // combine S0 <-> S1
    for (int p = tid; p < 4096; p += 512) {
      const int z = p >> 5, t = p & 31;
      const int zm = negrev(z), tm = negrev(jb0 + t) & 31;
      const float2 a  = T[z * PH3 + t];
      const float2 bb = T[SLICE + zm * PH3 + tm];
      const float f1r = 0.5f * (a.x + bb.x), f1i = 0.5f * (a.y - bb.y);
      const float f2r = 0.5f * (a.y + bb.y), f2i = 0.5f * (bb.x - a.x);
      const float gr = f1r * f2r + f1i * f2i;
      const float gi = f1i * f2r - f1r * f2i;
      T[z * PH3 + t] = make_float2(gr, gi);
      T[SLICE + zm * PH3 + tm] = make_float2(gr, -gi);
    }
  } else {                                      // combine within each slice
    for (int p = tid; p < 8192; p += 512) {
      const int s2 = p >> 12, z = (p >> 5) & 127, t = p & 31;
      const int zm = negrev(z), tm = negrev(s2 * 32 + t) & 31;
      const int pl = z * 32 + t, pm = zm * 32 + tm;
      if (pm < pl) continue;
      const float2 a  = T[s2 * SLICE + z * PH3 + t];
      const float2 bb = T[s2 * SLICE + zm * PH3 + tm];
      const float f1r = 0.5f * (a.x + bb.x), f1i = 0.5f * (a.y - bb.y);
      const float f2r = 0.5f * (a.y + bb.y), f2i = 0.5f * (bb.x - a.x);
      const float gr = f1r * f2r + f1i * f2i;
      const float gi = f1i * f2r - f1r * f2i;
      T[s2 * SLICE + z * PH3 + t] = make_float2(gr, gi);
      if (pm != pl) T[s2 * SLICE + zm * PH3 + tm] = make_float2(gr, -gi);
    }
  }
  __syncthreads();

#pragma unroll
  for (int j = 0; j < 16; ++j) c[j] = T[tb + (e + 8 * j) * PH3 + yc];
  F.inv(c);
#pragma unroll
  for (int j = 0; j < 16; ++j) T[tb + (e + 8 * j) * PH3 + yc] = c[j];
  __syncthreads();

  for (int p = tid; p < 2048; p += 512) {       // stage out
    const int z = p >> 4, w = (p & 15) << 1;
    *(float4*)&Z[base0 + (size_t)z * V + w] = *(const float4*)&T[z * PH3 + w];
  }
  for (int p = tid; p < 2048; p += 512) {
    const int z = p >> 4, w = (p & 15) << 1;
    *(float4*)&Z[base1 + (size_t)z * V + w] =
        *(const float4*)&T[SLICE + z * PH3 + w];
  }
}

// K3: per (b, z-plane-pair). Inverse y-FFT streamed from Z; inverse x-FFT
// from LDS rows; real part * 1/V^3 to out. Plane-1 Z reads prefetched.
__global__ __launch_bounds__(1024) void k_inv_xy(const float2* __restrict__ Z,
                                                 float* __restrict__ out) {
  __shared__ float2 s[V * PFP];
  const int tid = threadIdx.x, lane = tid & 63, wave = tid >> 6;
  const int o = lane >> 3, lq = lane & 7;
  const int b = blockIdx.x >> 6, zp = blockIdx.x & 63;
  const int z1 = zp * 2;
  WF16 F;
  F.init(lq);
  const int e = F.e;
  const int row = wave * 8 + o;   // x in pass 1, y in pass 2
  const float sc = 1.0f / 2097152.0f;  // 1/V^3
  float2 c[16];
  const size_t zb0 = ((size_t)(b * V + row) * V + z1) * V;
  {                               // plane 0: y-inverse
#pragma unroll
    for (int j = 0; j < 16; ++j) c[j] = Z[zb0 + e + 8 * j];
    F.inv(c);
#pragma unroll
    for (int j = 0; j < 16; ++j) s[(e + 8 * j) * PFP + row] = c[j];
  }
  __syncthreads();
  float2 pz[16];                  // prefetch plane 1
  {
    const size_t zb1 = zb0 + V;
#pragma unroll
    for (int j = 0; j < 16; ++j) pz[j] = Z[zb1 + e + 8 * j];
  }
  {                               // plane 0: x-inverse + store
    float2 d[16];
#pragma unroll
    for (int j = 0; j < 16; ++j) d[j] = s[row * PFP + e + 8 * j];
    F.inv(d);
    const size_t gg = (size_t)b * V3 + (size_t)z1 * V2 + (size_t)row * V;
#pragma unroll
    for (int j = 0; j < 16; ++j) out[gg + e + 8 * j] = d[j].x * sc;
  }
  __syncthreads();
  {                               // plane 1: y-inverse (from prefetch)
    F.inv(pz);
#pragma unroll
    for (int j = 0; j < 16; ++j) s[(e + 8 * j) * PFP + row] = pz[j];
  }
  __syncthreads();
  {                               // plane 1: x-inverse + store
    float2 d[16];
#pragma unroll
    for (int j = 0; j < 16; ++j) d[j] = s[row * PFP + e + 8 * j];
    F.inv(d);
    const size_t gg = (size_t)b * V3 + (size_t)(z1 + 1) * V2 + (size_t)row * V;
#pragma unroll
    for (int j = 0; j < 16; ++j) out[gg + e + 8 * j] = d[j].x * sc;
  }
}

extern "C" void kernel_launch(void* const* d_in, const int* in_sizes, int n_in,
                              void* d_out, int out_size, void* d_ws, size_t ws_size,
                              hipStream_t stream) {
  const float* v1 = (const float*)d_in[0];
  const float* v2 = (const float*)d_in[1];
  float* out = (float*)d_out;
  float2* Z  = (float2*)d_ws;  // NB*V3*8 = 128 MiB

  k_fwd_xy<<<NB * 64, 1024, 0, stream>>>(v1, v2, Z);
  k_z_fused<<<NB * 256, 512, 0, stream>>>(Z);   // 2 quarter-slices per block
  k_inv_xy<<<NB * 64, 1024, 0, stream>>>(Z, out);
}